// Round 4
// baseline (58.032 us; speedup 1.0000x reference)
//
#include <hip/hip_runtime.h>
#include <hip/hip_bf16.h>

#define NV 8192
#define NF 16384
#define BATCH 32
#define WORDS 256          // 8192 bits / 32 per row
#define MAXD 64            // distinct-degree cap; deg ~ Poisson(12), P(>64) ~ 0
#define BUILD_BLOCKS 256

typedef unsigned short ushort_t;

// ---------------------------------------------------------------------------
// Fused build kernel: scatter face edges into the bit-adjacency matrix
// (exact .set(-1) dedup semantics), grid barrier, then compact rows into
// transposed ushort neighbor lists.  256 blocks x 256 threads — co-resident
// by construction (graph serializes nodes; 4 waves/block, no LDS).
//   info[v] = deg | (cnt << 16);  deg = popcount(row) incl self (row-norm
//   divisor), cnt = list length excl self.  nbr sorted ascending (bit order)
//   -> downstream float sums bitwise deterministic.
// ---------------------------------------------------------------------------
__global__ __launch_bounds__(256)
void build_kernel(const int* __restrict__ faces,
                  unsigned* __restrict__ adj,
                  int* __restrict__ bar,
                  unsigned* __restrict__ info,
                  ushort_t* __restrict__ nbr) {
    const int tid = blockIdx.x * 256 + threadIdx.x;

    // ---- phase 1: scatter ----
    if (tid < NF) {
        int a = faces[tid * 3 + 0];
        int b = faces[tid * 3 + 1];
        int c = faces[tid * 3 + 2];
        #define SETBIT(r, cc) atomicOr(&adj[(r) * WORDS + ((cc) >> 5)], 1u << ((cc) & 31))
        SETBIT(a, b); SETBIT(b, a);
        SETBIT(b, c); SETBIT(c, b);
        SETBIT(c, a); SETBIT(a, c);
        #undef SETBIT
    }

    // ---- grid barrier (release arrival, acquire spin, agent scope) ----
    __syncthreads();   // compiler drains vmcnt(0) before s_barrier -> atomics done
    if (threadIdx.x == 0) {
        __hip_atomic_fetch_add(bar, 1, __ATOMIC_ACQ_REL, __HIP_MEMORY_SCOPE_AGENT);
        while (__hip_atomic_load(bar, __ATOMIC_ACQUIRE, __HIP_MEMORY_SCOPE_AGENT)
               < BUILD_BLOCKS) { __builtin_amdgcn_s_sleep(1); }
    }
    __syncthreads();

    // ---- phase 2: compact (one wave per vertex, 8 vertices per wave) ----
    const int lane = threadIdx.x & 63;
    const int gw   = tid >> 6;                 // global wave id: 0..1023

    for (int v = gw; v < NV; v += (BUILD_BLOCKS * 256) / 64) {
        const uint4 wq = *reinterpret_cast<const uint4*>(
            adj + (size_t)v * WORDS + lane * 4);
        unsigned wm[4] = {wq.x, wq.y, wq.z, wq.w};

        int pc = __popc(wm[0]) + __popc(wm[1]) + __popc(wm[2]) + __popc(wm[3]);

        // remove self-bit from the list (kept in deg)
        const int selfword = v >> 5;
        const int base     = lane * 4;
        int c = pc;
        if (selfword >= base && selfword < base + 4) {
            unsigned m = 1u << (v & 31);
            if (wm[selfword - base] & m) { wm[selfword - base] &= ~m; c -= 1; }
        }

        // wave-wide inclusive scan of c (list offsets) + totals
        int incl = c;
        #pragma unroll
        for (int off = 1; off < 64; off <<= 1) {
            int o = __shfl_up(incl, off);
            if (lane >= off) incl += o;
        }
        const int ofs     = incl - c;
        const int total_c = __shfl(incl, 63);

        int pct = pc;
        #pragma unroll
        for (int off = 1; off < 64; off <<= 1) pct += __shfl_xor(pct, off);

        int idx = ofs;
        #pragma unroll
        for (int j = 0; j < 4; ++j) {
            unsigned bits = wm[j];
            const int wbase = (base + j) << 5;
            while (bits) {
                int bpos = __ffs(bits) - 1;
                bits &= bits - 1;
                if (idx < MAXD) nbr[idx * NV + v] = (ushort_t)(wbase + bpos);
                ++idx;
            }
        }
        if (lane == 0)
            info[v] = (unsigned)pct | ((unsigned)(total_c < MAXD ? total_c : MAXD) << 16);
    }
}

// ---------------------------------------------------------------------------
// Gather + fused final reduction. Grid = 32 batches x 8 vertex-groups,
// 1024 thr/block. Stage x[b] (96 KB) in LDS; thread t owns v = g*1024+t:
// y = x[v] - (sum of LDS neighbors)/deg, r = |y|^2; deterministic block
// reduce -> partials; last block writes out[b] = sum_g partials[b*8+g]/NV.
// ---------------------------------------------------------------------------
__global__ __launch_bounds__(1024)
void gather_kernel(const float* __restrict__ x,
                   const unsigned* __restrict__ info,
                   const ushort_t* __restrict__ nbr,
                   float* __restrict__ partials,
                   int* __restrict__ counter,
                   float* __restrict__ out) {
    __shared__ float lx[NV * 3];     // 96 KiB
    __shared__ float red[16];
    __shared__ int isLast;

    const int t = threadIdx.x;
    const int b = blockIdx.x >> 3;
    const int g = blockIdx.x & 7;

    // stage x[b]: 24576 floats = 6144 float4, coalesced
    const float4* xs = reinterpret_cast<const float4*>(x + (size_t)b * NV * 3);
    float4* ls = reinterpret_cast<float4*>(lx);
    #pragma unroll
    for (int i = 0; i < 6; ++i) ls[t + i * 1024] = xs[t + i * 1024];
    __syncthreads();

    const int v = g * 1024 + t;
    const unsigned iv = info[v];
    const int dv = (int)(iv & 0xFFFFu);
    const int cv = (int)(iv >> 16);

    float s0 = 0.f, s1 = 0.f, s2 = 0.f;
    for (int k = 0; k < cv; ++k) {
        const int w = (int)nbr[k * NV + v] * 3;
        s0 += lx[w];
        s1 += lx[w + 1];
        s2 += lx[w + 2];
    }

    float r = 0.f;
    if (dv > 0) {
        const float inv = 1.0f / (float)dv;
        const float y0 = lx[v * 3]     - s0 * inv;
        const float y1 = lx[v * 3 + 1] - s1 * inv;
        const float y2 = lx[v * 3 + 2] - s2 * inv;
        r = y0 * y0 + y1 * y1 + y2 * y2;
    }

    // deterministic block reduction over 1024 threads
    #pragma unroll
    for (int off = 32; off > 0; off >>= 1) r += __shfl_down(r, off);
    if ((t & 63) == 0) red[t >> 6] = r;
    __syncthreads();

    if (t == 0) {
        float s = 0.f;
        #pragma unroll
        for (int i = 0; i < 16; ++i) s += red[i];
        __hip_atomic_store(&partials[blockIdx.x], s,
                           __ATOMIC_RELAXED, __HIP_MEMORY_SCOPE_AGENT);
        int old = __hip_atomic_fetch_add(counter, 1,
                                         __ATOMIC_ACQ_REL, __HIP_MEMORY_SCOPE_AGENT);
        isLast = (old == (int)gridDim.x - 1);
    }
    __syncthreads();

    if (isLast && t < BATCH) {
        float s = 0.f;
        #pragma unroll
        for (int gg = 0; gg < 8; ++gg)
            s += __hip_atomic_load(&partials[t * 8 + gg],
                                   __ATOMIC_RELAXED, __HIP_MEMORY_SCOPE_AGENT);
        out[t] = s / (float)NV;
    }
}

extern "C" void kernel_launch(void* const* d_in, const int* in_sizes, int n_in,
                              void* d_out, int out_size, void* d_ws, size_t ws_size,
                              hipStream_t stream) {
    const float* x   = (const float*)d_in[0];   // (32, 8192, 3) f32
    const int* faces = (const int*)d_in[1];     // (16384, 3) i32
    float* out       = (float*)d_out;           // (32,) f32

    char* ws = (char*)d_ws;
    unsigned* adj    = (unsigned*)ws;                                  // 8 MiB
    int*      bar    = (int*)(ws + (size_t)NV * WORDS * 4);            // 4 B
    int*      counter= bar + 1;                                        // 4 B
    ushort_t* nbr    = (ushort_t*)(bar + 64);                          // 1 MiB
    unsigned* info   = (unsigned*)((char*)nbr + (size_t)MAXD * NV * 2);// 32 KiB
    float* partials  = (float*)(info + NV);                            // 1 KiB

    // one memset zeroes bitmap + barrier + completion counter (every call)
    hipMemsetAsync(adj, 0, (size_t)NV * WORDS * 4 + 256, stream);

    build_kernel<<<BUILD_BLOCKS, 256, 0, stream>>>(faces, adj, bar, info, nbr);
    gather_kernel<<<BATCH * 8, 1024, 0, stream>>>(x, info, nbr, partials, counter, out);
}

// Round 5
// 31.540 us; speedup vs baseline: 1.8400x; 1.8400x over previous
//
#include <hip/hip_runtime.h>

#define NV 8192
#define NF 16384
#define BATCH 32
#define VPB 32            // vertices per build block (256 blocks total)
#define CAP 64            // raw candidate slots per vertex; raw deg = 2*Poisson(6), P(>64) ~ 0

typedef unsigned short ushort_t;

// ---------------------------------------------------------------------------
// Node 1: build. Each block owns 32 vertices, scans ALL faces (192 KB,
// L2-resident), pushes candidates for its vertices into LDS buckets, then
// dedups (exact .set(-1) semantics) and emits VALUE-SORTED ushort neighbor
// lists (transposed) -> downstream float sums are bitwise deterministic even
// though LDS-atomic push order is not.
//   info[v] = deg | (cnt << 16); deg = #distinct incl self (row-norm divisor),
//   cnt = list length excl self.
// Also zeroes the gather kernel's last-block counter (saves a memset node).
// ---------------------------------------------------------------------------
__global__ __launch_bounds__(1024)
void build_kernel(const int* __restrict__ faces,
                  unsigned* __restrict__ info,
                  ushort_t* __restrict__ nbr,
                  int* __restrict__ counter) {
    __shared__ ushort_t cand[VPB][CAP];   // 4 KiB
    __shared__ int ccnt[VPB];

    const int t    = threadIdx.x;
    const int base = blockIdx.x * VPB;

    if (t < VPB) ccnt[t] = 0;
    if (blockIdx.x == 0 && t == 0) *counter = 0;   // reset for gather's last-block logic
    __syncthreads();

    // ---- face scan: 16 coalesced faces per thread ----
    #pragma unroll
    for (int i = 0; i < NF / 1024; ++i) {
        const int f = i * 1024 + t;
        const int a = faces[3 * f + 0];
        const int b = faces[3 * f + 1];
        const int c = faces[3 * f + 2];
        // directed edges (a,b),(b,a),(b,c),(c,b),(c,a),(a,c):
        // row a gets {b,c}; row b gets {a,c}; row c gets {b,a}.
        #define PUSH(vi, w) { int p = atomicAdd(&ccnt[vi], 1); \
                              if (p < CAP) cand[vi][p] = (ushort_t)(w); }
        const unsigned ra = (unsigned)(a - base);
        const unsigned rb = (unsigned)(b - base);
        const unsigned rc = (unsigned)(c - base);
        if (ra < VPB) { PUSH(ra, b); PUSH(ra, c); }
        if (rb < VPB) { PUSH(rb, a); PUSH(rb, c); }
        if (rc < VPB) { PUSH(rc, b); PUSH(rc, a); }
        #undef PUSH
    }
    __syncthreads();

    // ---- dedup + value-rank: one wave per vertex, 2 vertices per wave ----
    const int lane = t & 63;
    const int wid  = t >> 6;              // 0..15
    #pragma unroll
    for (int s = 0; s < 2; ++s) {
        const int vi = wid * 2 + s;       // 0..31
        const int v  = base + vi;
        int craw = ccnt[vi]; if (craw > CAP) craw = CAP;

        int val = (lane < craw) ? (int)cand[vi][lane] : 0x10000;  // sentinel

        // first-occurrence dedup (the kept SET is order-independent)
        bool dup = false;
        for (int j = 0; j + 1 < craw; ++j) {
            int vj = __shfl(val, j);
            if (lane > j && val == vj) dup = true;
        }
        const bool valid = (lane < craw) && !dup;        // distinct, incl self
        const int  deg   = __popcll(__ballot(valid));
        const bool keep  = valid && (val != v);          // list excludes self
        const int  cnt   = __popcll(__ballot(keep));

        // rank by value (distinct) -> sorted ascending, deterministic
        int rank = 0;
        for (int j = 0; j < craw; ++j) {
            int vj = __shfl(val, j);
            int kj = __shfl(keep ? 1 : 0, j);
            if (kj && vj < val) ++rank;
        }

        if (keep) nbr[rank * NV + v] = (ushort_t)val;    // coalesced-ish 2B writes
        if (lane == 0) info[v] = (unsigned)deg | ((unsigned)cnt << 16);
    }
}

// ---------------------------------------------------------------------------
// Node 2: gather + fused final reduction (proven R3/R4 structure).
// Grid = 32 batches x 8 vertex-groups, 1024 thr/block. Stage x[b] (96 KB) in
// LDS; thread t owns v = g*1024+t: y = x[v] - (sum of sorted neighbors)/deg,
// r = |y|^2; deterministic block reduce -> partials; last block finishes.
// ---------------------------------------------------------------------------
__global__ __launch_bounds__(1024)
void gather_kernel(const float* __restrict__ x,
                   const unsigned* __restrict__ info,
                   const ushort_t* __restrict__ nbr,
                   float* __restrict__ partials,
                   int* __restrict__ counter,
                   float* __restrict__ out) {
    __shared__ float lx[NV * 3];     // 96 KiB
    __shared__ float red[16];
    __shared__ int isLast;

    const int t = threadIdx.x;
    const int b = blockIdx.x >> 3;
    const int g = blockIdx.x & 7;

    // stage x[b]: 24576 floats = 6144 float4, coalesced
    const float4* xs = reinterpret_cast<const float4*>(x + (size_t)b * NV * 3);
    float4* ls = reinterpret_cast<float4*>(lx);
    #pragma unroll
    for (int i = 0; i < 6; ++i) ls[t + i * 1024] = xs[t + i * 1024];
    __syncthreads();

    const int v = g * 1024 + t;
    const unsigned iv = info[v];
    const int dv = (int)(iv & 0xFFFFu);
    const int cv = (int)(iv >> 16);

    float s0 = 0.f, s1 = 0.f, s2 = 0.f;
    for (int k = 0; k < cv; ++k) {
        const int w = (int)nbr[k * NV + v] * 3;   // coalesced ushort load
        s0 += lx[w];
        s1 += lx[w + 1];
        s2 += lx[w + 2];
    }

    float r = 0.f;
    if (dv > 0) {
        const float inv = 1.0f / (float)dv;
        const float y0 = lx[v * 3]     - s0 * inv;
        const float y1 = lx[v * 3 + 1] - s1 * inv;
        const float y2 = lx[v * 3 + 2] - s2 * inv;
        r = y0 * y0 + y1 * y1 + y2 * y2;
    }

    // deterministic block reduction over 1024 threads
    #pragma unroll
    for (int off = 32; off > 0; off >>= 1) r += __shfl_down(r, off);
    if ((t & 63) == 0) red[t >> 6] = r;
    __syncthreads();

    if (t == 0) {
        float s = 0.f;
        #pragma unroll
        for (int i = 0; i < 16; ++i) s += red[i];
        __hip_atomic_store(&partials[blockIdx.x], s,
                           __ATOMIC_RELAXED, __HIP_MEMORY_SCOPE_AGENT);
        int old = __hip_atomic_fetch_add(counter, 1,
                                         __ATOMIC_ACQ_REL, __HIP_MEMORY_SCOPE_AGENT);
        isLast = (old == (int)gridDim.x - 1);
    }
    __syncthreads();

    if (isLast && t < BATCH) {
        float s = 0.f;
        #pragma unroll
        for (int gg = 0; gg < 8; ++gg)
            s += __hip_atomic_load(&partials[t * 8 + gg],
                                   __ATOMIC_RELAXED, __HIP_MEMORY_SCOPE_AGENT);
        out[t] = s / (float)NV;
    }
}

extern "C" void kernel_launch(void* const* d_in, const int* in_sizes, int n_in,
                              void* d_out, int out_size, void* d_ws, size_t ws_size,
                              hipStream_t stream) {
    const float* x   = (const float*)d_in[0];   // (32, 8192, 3) f32
    const int* faces = (const int*)d_in[1];     // (16384, 3) i32
    float* out       = (float*)d_out;           // (32,) f32

    char* ws = (char*)d_ws;
    ushort_t* nbr     = (ushort_t*)ws;                         // 1 MiB (64 x 8192 ushort)
    unsigned* info    = (unsigned*)(ws + (size_t)CAP * NV * 2);// 32 KiB
    int*      counter = (int*)(info + NV);                     // 4 B (zeroed by build)
    float*    partials= (float*)(counter + 64);                // 1 KiB

    build_kernel <<<NV / VPB, 1024, 0, stream>>>(faces, info, nbr, counter);
    gather_kernel<<<BATCH * 8, 1024, 0, stream>>>(x, info, nbr, partials, counter, out);
}

// Round 6
// 25.115 us; speedup vs baseline: 2.3107x; 1.2558x over previous
//
#include <hip/hip_runtime.h>

#define NV 8192
#define NF 16384
#define BATCH 32
#define VPB 32            // vertices per build block (256 blocks)
#define WORDS 256         // 8192 bits / 32 per row
#define MAXD 64           // list capacity; distinct deg ~ Poisson(12), P(>64) ~ 0

typedef unsigned short ushort_t;

// ---------------------------------------------------------------------------
// Node 1: build. Each block owns 32 vertices with a 32 KiB LDS bit-adjacency
// (32 rows x 8192 bits). Scan ALL faces (192 KB, L2-resident) with uint4
// loads, atomicOr bits for in-range rows (exact .set(-1) dedup semantics,
// order-free), then compact each row (R2's proven fixed-trip compaction)
// into value-sorted transposed ushort neighbor lists.
//   info[v] = deg | (cnt << 16); deg = popcount incl self (row-norm divisor),
//   cnt = list length excl self. Sorted lists -> deterministic gather sums.
// ---------------------------------------------------------------------------
__global__ __launch_bounds__(1024)
void build_kernel(const int* __restrict__ faces,
                  unsigned* __restrict__ info,
                  ushort_t* __restrict__ nbr,
                  int* __restrict__ counter) {
    __shared__ unsigned bits[VPB][WORDS];   // 32 KiB

    const int t    = threadIdx.x;
    const int base = blockIdx.x * VPB;

    // zero bitmap: 8192 words = 2048 uint4, 2 per thread
    uint4* bz = reinterpret_cast<uint4*>(&bits[0][0]);
    bz[t]        = make_uint4(0, 0, 0, 0);
    bz[t + 1024] = make_uint4(0, 0, 0, 0);
    if (blockIdx.x == 0 && t == 0) *counter = 0;   // for gather's last-block logic
    __syncthreads();

    // ---- face scan: 4 faces = 3 uint4 per thread per iteration ----
    const uint4* f4 = reinterpret_cast<const uint4*>(faces);   // 12288 uint4
    #define SETB(vi, w) atomicOr(&bits[vi][(int)(w) >> 5], 1u << ((w) & 31))
    #define PROC(a, b, c) { \
        const unsigned ra = (unsigned)((int)(a) - base); \
        const unsigned rb = (unsigned)((int)(b) - base); \
        const unsigned rc = (unsigned)((int)(c) - base); \
        if (ra < VPB) { SETB(ra, (b)); SETB(ra, (c)); } \
        if (rb < VPB) { SETB(rb, (a)); SETB(rb, (c)); } \
        if (rc < VPB) { SETB(rc, (b)); SETB(rc, (a)); } }
    #pragma unroll
    for (int i = 0; i < NF / 4096; ++i) {          // 4 iterations
        const int j = (i * 1024 + t) * 3;
        const uint4 p = f4[j], q = f4[j + 1], r = f4[j + 2];
        PROC(p.x, p.y, p.z);
        PROC(p.w, q.x, q.y);
        PROC(q.z, q.w, r.x);
        PROC(r.y, r.z, r.w);
    }
    #undef PROC
    #undef SETB
    __syncthreads();

    // ---- compact: one wave per vertex, 2 vertices per wave (fixed-trip) ----
    const int lane = t & 63;
    const int wid  = t >> 6;                       // 0..15
    #pragma unroll
    for (int s = 0; s < 2; ++s) {
        const int vi = wid * 2 + s;                // 0..31
        const int v  = base + vi;

        const uint4 wq = reinterpret_cast<const uint4*>(&bits[vi][0])[lane];
        unsigned wm[4] = {wq.x, wq.y, wq.z, wq.w};

        int pc = __popc(wm[0]) + __popc(wm[1]) + __popc(wm[2]) + __popc(wm[3]);

        // remove self-bit from the list (kept in deg)
        const int selfword = v >> 5;               // word index of bit v... (bit v of row)
        const int wbase0   = lane * 4;
        int c = pc;
        if (selfword >= wbase0 && selfword < wbase0 + 4) {
            const unsigned m = 1u << (v & 31);
            if (wm[selfword - wbase0] & m) { wm[selfword - wbase0] &= ~m; c -= 1; }
        }

        // wave-wide inclusive scan of c (list offsets) + totals
        int incl = c;
        #pragma unroll
        for (int off = 1; off < 64; off <<= 1) {
            int o = __shfl_up(incl, off);
            if (lane >= off) incl += o;
        }
        const int ofs     = incl - c;
        const int total_c = __shfl(incl, 63);

        int pct = pc;
        #pragma unroll
        for (int off = 1; off < 64; off <<= 1) pct += __shfl_xor(pct, off);

        int idx = ofs;
        #pragma unroll
        for (int jw = 0; jw < 4; ++jw) {
            unsigned bb = wm[jw];
            const int wb = (wbase0 + jw) << 5;
            while (bb) {
                const int bpos = __ffs(bb) - 1;
                bb &= bb - 1;
                if (idx < MAXD) nbr[idx * NV + v] = (ushort_t)(wb + bpos);
                ++idx;
            }
        }
        if (lane == 0)
            info[v] = (unsigned)pct |
                      ((unsigned)(total_c < MAXD ? total_c : MAXD) << 16);
    }
}

// ---------------------------------------------------------------------------
// Node 2: gather + fused final reduction (unchanged from R5 — proven).
// Grid = 32 batches x 8 vertex-groups, 1024 thr/block. Stage x[b] (96 KB) in
// LDS; thread t owns v = g*1024+t: y = x[v] - (sum of sorted neighbors)/deg,
// r = |y|^2; deterministic block reduce -> partials; last block finishes.
// ---------------------------------------------------------------------------
__global__ __launch_bounds__(1024)
void gather_kernel(const float* __restrict__ x,
                   const unsigned* __restrict__ info,
                   const ushort_t* __restrict__ nbr,
                   float* __restrict__ partials,
                   int* __restrict__ counter,
                   float* __restrict__ out) {
    __shared__ float lx[NV * 3];     // 96 KiB
    __shared__ float red[16];
    __shared__ int isLast;

    const int t = threadIdx.x;
    const int b = blockIdx.x >> 3;
    const int g = blockIdx.x & 7;

    // stage x[b]: 24576 floats = 6144 float4, coalesced
    const float4* xs = reinterpret_cast<const float4*>(x + (size_t)b * NV * 3);
    float4* ls = reinterpret_cast<float4*>(lx);
    #pragma unroll
    for (int i = 0; i < 6; ++i) ls[t + i * 1024] = xs[t + i * 1024];
    __syncthreads();

    const int v = g * 1024 + t;
    const unsigned iv = info[v];
    const int dv = (int)(iv & 0xFFFFu);
    const int cv = (int)(iv >> 16);

    float s0 = 0.f, s1 = 0.f, s2 = 0.f;
    for (int k = 0; k < cv; ++k) {
        const int w = (int)nbr[k * NV + v] * 3;   // coalesced ushort load
        s0 += lx[w];
        s1 += lx[w + 1];
        s2 += lx[w + 2];
    }

    float r = 0.f;
    if (dv > 0) {
        const float inv = 1.0f / (float)dv;
        const float y0 = lx[v * 3]     - s0 * inv;
        const float y1 = lx[v * 3 + 1] - s1 * inv;
        const float y2 = lx[v * 3 + 2] - s2 * inv;
        r = y0 * y0 + y1 * y1 + y2 * y2;
    }

    // deterministic block reduction over 1024 threads
    #pragma unroll
    for (int off = 32; off > 0; off >>= 1) r += __shfl_down(r, off);
    if ((t & 63) == 0) red[t >> 6] = r;
    __syncthreads();

    if (t == 0) {
        float s = 0.f;
        #pragma unroll
        for (int i = 0; i < 16; ++i) s += red[i];
        __hip_atomic_store(&partials[blockIdx.x], s,
                           __ATOMIC_RELAXED, __HIP_MEMORY_SCOPE_AGENT);
        int old = __hip_atomic_fetch_add(counter, 1,
                                         __ATOMIC_ACQ_REL, __HIP_MEMORY_SCOPE_AGENT);
        isLast = (old == (int)gridDim.x - 1);
    }
    __syncthreads();

    if (isLast && t < BATCH) {
        float s = 0.f;
        #pragma unroll
        for (int gg = 0; gg < 8; ++gg)
            s += __hip_atomic_load(&partials[t * 8 + gg],
                                   __ATOMIC_RELAXED, __HIP_MEMORY_SCOPE_AGENT);
        out[t] = s / (float)NV;
    }
}

extern "C" void kernel_launch(void* const* d_in, const int* in_sizes, int n_in,
                              void* d_out, int out_size, void* d_ws, size_t ws_size,
                              hipStream_t stream) {
    const float* x   = (const float*)d_in[0];   // (32, 8192, 3) f32
    const int* faces = (const int*)d_in[1];     // (16384, 3) i32
    float* out       = (float*)d_out;           // (32,) f32

    char* ws = (char*)d_ws;
    ushort_t* nbr     = (ushort_t*)ws;                          // 1 MiB (64 x 8192 ushort)
    unsigned* info    = (unsigned*)(ws + (size_t)MAXD * NV * 2);// 32 KiB
    int*      counter = (int*)(info + NV);                      // 4 B (zeroed by build)
    float*    partials= (float*)(counter + 64);                 // 1 KiB

    build_kernel <<<NV / VPB, 1024, 0, stream>>>(faces, info, nbr, counter);
    gather_kernel<<<BATCH * 8, 1024, 0, stream>>>(x, info, nbr, partials, counter, out);
}

// Round 7
// 24.514 us; speedup vs baseline: 2.3673x; 1.0245x over previous
//
#include <hip/hip_runtime.h>

#define NV 8192
#define NF 16384
#define BATCH 32
#define VPB 32            // vertices per build block (256 blocks)
#define WORDS 256         // 8192 bits / 32 per row
#define MAXD 64           // list capacity; P(distinct deg > 64) ~ 1e-15 per vertex

typedef unsigned short ushort_t;

// ---------------------------------------------------------------------------
// Node 1: build (R6 structure, proven). Per-block 32 KiB LDS bit-adjacency
// (32 rows x 8192 bits); scan ALL faces with uint4 loads; atomicOr = exact
// .set(-1) dedup semantics; fixed-trip compaction emits VALUE-SORTED
// neighbor lists, now ROW-MAJOR nbr[v][64] (128 B rows) for the gather's
// vectorized id loads.
//   info[v] = deg | (cnt << 16); deg = popcount incl self (row-norm divisor),
//   cnt = list length excl self.
// ---------------------------------------------------------------------------
__global__ __launch_bounds__(1024)
void build_kernel(const int* __restrict__ faces,
                  unsigned* __restrict__ info,
                  ushort_t* __restrict__ nbr,
                  int* __restrict__ counter) {
    __shared__ unsigned bits[VPB][WORDS];   // 32 KiB

    const int t    = threadIdx.x;
    const int base = blockIdx.x * VPB;

    // zero bitmap: 8192 words = 2048 uint4, 2 per thread
    uint4* bz = reinterpret_cast<uint4*>(&bits[0][0]);
    bz[t]        = make_uint4(0, 0, 0, 0);
    bz[t + 1024] = make_uint4(0, 0, 0, 0);
    if (blockIdx.x == 0 && t == 0) *counter = 0;   // for gather's last-block logic
    __syncthreads();

    // ---- face scan: 4 faces = 3 uint4 per thread per iteration ----
    const uint4* f4 = reinterpret_cast<const uint4*>(faces);   // 12288 uint4
    #define SETB(vi, w) atomicOr(&bits[vi][(int)(w) >> 5], 1u << ((w) & 31))
    #define PROC(a, b, c) { \
        const unsigned ra = (unsigned)((int)(a) - base); \
        const unsigned rb = (unsigned)((int)(b) - base); \
        const unsigned rc = (unsigned)((int)(c) - base); \
        if (ra < VPB) { SETB(ra, (b)); SETB(ra, (c)); } \
        if (rb < VPB) { SETB(rb, (a)); SETB(rb, (c)); } \
        if (rc < VPB) { SETB(rc, (b)); SETB(rc, (a)); } }
    #pragma unroll
    for (int i = 0; i < NF / 4096; ++i) {          // 4 iterations
        const int j = (i * 1024 + t) * 3;
        const uint4 p = f4[j], q = f4[j + 1], r = f4[j + 2];
        PROC(p.x, p.y, p.z);
        PROC(p.w, q.x, q.y);
        PROC(q.z, q.w, r.x);
        PROC(r.y, r.z, r.w);
    }
    #undef PROC
    #undef SETB
    __syncthreads();

    // ---- compact: one wave per vertex, 2 vertices per wave (fixed-trip) ----
    const int lane = t & 63;
    const int wid  = t >> 6;                       // 0..15
    #pragma unroll
    for (int s = 0; s < 2; ++s) {
        const int vi = wid * 2 + s;                // 0..31
        const int v  = base + vi;

        const uint4 wq = reinterpret_cast<const uint4*>(&bits[vi][0])[lane];
        unsigned wm[4] = {wq.x, wq.y, wq.z, wq.w};

        int pc = __popc(wm[0]) + __popc(wm[1]) + __popc(wm[2]) + __popc(wm[3]);

        // remove self-bit from the list (kept in deg)
        const int selfword = v >> 5;
        const int wbase0   = lane * 4;
        int c = pc;
        if (selfword >= wbase0 && selfword < wbase0 + 4) {
            const unsigned m = 1u << (v & 31);
            if (wm[selfword - wbase0] & m) { wm[selfword - wbase0] &= ~m; c -= 1; }
        }

        // wave-wide inclusive scan of c (list offsets) + totals
        int incl = c;
        #pragma unroll
        for (int off = 1; off < 64; off <<= 1) {
            int o = __shfl_up(incl, off);
            if (lane >= off) incl += o;
        }
        const int ofs     = incl - c;
        const int total_c = __shfl(incl, 63);

        int pct = pc;
        #pragma unroll
        for (int off = 1; off < 64; off <<= 1) pct += __shfl_xor(pct, off);

        int idx = ofs;
        #pragma unroll
        for (int jw = 0; jw < 4; ++jw) {
            unsigned bb = wm[jw];
            const int wb = (wbase0 + jw) << 5;
            while (bb) {
                const int bpos = __ffs(bb) - 1;
                bb &= bb - 1;
                if (idx < MAXD) nbr[(size_t)v * MAXD + idx] = (ushort_t)(wb + bpos);
                ++idx;
            }
        }
        if (lane == 0)
            info[v] = (unsigned)pct |
                      ((unsigned)(total_c < MAXD ? total_c : MAXD) << 16);
    }
}

// ---------------------------------------------------------------------------
// Node 2: gather + fused final reduction.
// Grid = 32 batches x 8 vertex-groups, 1024 thr/block; x[b] (96 KB) in LDS.
// NEW: neighbor ids for k<32 are loaded up-front with 4 independent uint4
// loads (coalesced 64 B/thread), then a fully-unrolled predicated LDS
// accumulate with wave-uniform early exit at kmax = wave-max(cv). Rare
// global tail handles cv>32. Sum order still ascending -> deterministic.
// ---------------------------------------------------------------------------
__global__ __launch_bounds__(1024)
void gather_kernel(const float* __restrict__ x,
                   const unsigned* __restrict__ info,
                   const ushort_t* __restrict__ nbr,
                   float* __restrict__ partials,
                   int* __restrict__ counter,
                   float* __restrict__ out) {
    __shared__ float lx[NV * 3];     // 96 KiB
    __shared__ float red[16];
    __shared__ int isLast;

    const int t = threadIdx.x;
    const int b = blockIdx.x >> 3;
    const int g = blockIdx.x & 7;

    // stage x[b]: 24576 floats = 6144 float4, coalesced
    const float4* xs = reinterpret_cast<const float4*>(x + (size_t)b * NV * 3);
    float4* ls = reinterpret_cast<float4*>(lx);
    #pragma unroll
    for (int i = 0; i < 6; ++i) ls[t + i * 1024] = xs[t + i * 1024];

    const int v = g * 1024 + t;
    const unsigned iv = info[v];
    const int dv = (int)(iv & 0xFFFFu);
    const int cv = (int)(iv >> 16);

    // issue the 4 neighbor-id vector loads early (independent of LDS staging)
    const uint4* np = reinterpret_cast<const uint4*>(nbr + (size_t)v * MAXD);
    const uint4 n0 = np[0], n1 = np[1], n2 = np[2], n3 = np[3];
    const unsigned nd[16] = {n0.x, n0.y, n0.z, n0.w,
                             n1.x, n1.y, n1.z, n1.w,
                             n2.x, n2.y, n2.z, n2.w,
                             n3.x, n3.y, n3.z, n3.w};

    // wave-uniform trip bound
    int kmax = cv;
    #pragma unroll
    for (int off = 1; off < 64; off <<= 1) {
        int o = __shfl_xor(kmax, off);
        kmax = kmax > o ? kmax : o;
    }

    __syncthreads();   // staging complete

    float s0 = 0.f, s1 = 0.f, s2 = 0.f;
    #pragma unroll
    for (int k = 0; k < 32; ++k) {                 // fully unrolled: nd[] static
        if (k >= kmax) break;                      // wave-uniform early exit
        if (k < cv) {
            const int w = (int)((nd[k >> 1] >> ((k & 1) * 16)) & 0xFFFFu) * 3;
            s0 += lx[w];
            s1 += lx[w + 1];
            s2 += lx[w + 2];
        }
    }
    if (kmax > 32) {                               // rare (expected ~0-1 vertices)
        for (int k = 32; k < cv; ++k) {
            const int w = (int)nbr[(size_t)v * MAXD + k] * 3;
            s0 += lx[w];
            s1 += lx[w + 1];
            s2 += lx[w + 2];
        }
    }

    float r = 0.f;
    if (dv > 0) {
        const float inv = 1.0f / (float)dv;
        const float y0 = lx[v * 3]     - s0 * inv;
        const float y1 = lx[v * 3 + 1] - s1 * inv;
        const float y2 = lx[v * 3 + 2] - s2 * inv;
        r = y0 * y0 + y1 * y1 + y2 * y2;
    }

    // deterministic block reduction over 1024 threads
    #pragma unroll
    for (int off = 32; off > 0; off >>= 1) r += __shfl_down(r, off);
    if ((t & 63) == 0) red[t >> 6] = r;
    __syncthreads();

    if (t == 0) {
        float s = 0.f;
        #pragma unroll
        for (int i = 0; i < 16; ++i) s += red[i];
        __hip_atomic_store(&partials[blockIdx.x], s,
                           __ATOMIC_RELAXED, __HIP_MEMORY_SCOPE_AGENT);
        int old = __hip_atomic_fetch_add(counter, 1,
                                         __ATOMIC_ACQ_REL, __HIP_MEMORY_SCOPE_AGENT);
        isLast = (old == (int)gridDim.x - 1);
    }
    __syncthreads();

    if (isLast && t < BATCH) {
        float s = 0.f;
        #pragma unroll
        for (int gg = 0; gg < 8; ++gg)
            s += __hip_atomic_load(&partials[t * 8 + gg],
                                   __ATOMIC_RELAXED, __HIP_MEMORY_SCOPE_AGENT);
        out[t] = s / (float)NV;
    }
}

extern "C" void kernel_launch(void* const* d_in, const int* in_sizes, int n_in,
                              void* d_out, int out_size, void* d_ws, size_t ws_size,
                              hipStream_t stream) {
    const float* x   = (const float*)d_in[0];   // (32, 8192, 3) f32
    const int* faces = (const int*)d_in[1];     // (16384, 3) i32
    float* out       = (float*)d_out;           // (32,) f32

    char* ws = (char*)d_ws;
    ushort_t* nbr     = (ushort_t*)ws;                          // 1 MiB: [8192][64] ushort
    unsigned* info    = (unsigned*)(ws + (size_t)MAXD * NV * 2);// 32 KiB
    int*      counter = (int*)(info + NV);                      // 4 B (zeroed by build)
    float*    partials= (float*)(counter + 64);                 // 1 KiB

    build_kernel <<<NV / VPB, 1024, 0, stream>>>(faces, info, nbr, counter);
    gather_kernel<<<BATCH * 8, 1024, 0, stream>>>(x, info, nbr, partials, counter, out);
}